// Round 1
// baseline (1974.850 us; speedup 1.0000x reference)
//
#include <hip/hip_runtime.h>
#include <hip/hip_bf16.h>
#include <math.h>

// Problem constants
#define D_MODEL 1024
#define D_FF    4096
#define N_EXP   8
#define TOKENS  2048          // 2 * 1024
#define THRESH  0.8f
#define EPS_R   1e-6f

#define FINAL_SIZE (TOKENS * D_MODEL)   // 2097152

typedef unsigned short ushort_t;
typedef __attribute__((ext_vector_type(4))) float f32x4;
typedef __attribute__((ext_vector_type(8))) short bf16x8;

__device__ __forceinline__ unsigned short f2bf(float f) {
    unsigned u = __builtin_bit_cast(unsigned, f);
    unsigned r = (u + 0x7FFFu + ((u >> 16) & 1u)) >> 16;
    return (unsigned short)r;
}
__device__ __forceinline__ float bf2f(unsigned short b) {
    unsigned u = ((unsigned)b) << 16;
    return __builtin_bit_cast(float, u);
}

// ---------------------------------------------------------------- convert x
__global__ __launch_bounds__(256) void convert_x_kernel(const float* __restrict__ x,
                                                        ushort_t* __restrict__ xbf) {
    int i = blockIdx.x * 256 + threadIdx.x;   // each handles 4 floats
    const float4 v = reinterpret_cast<const float4*>(x)[i];
    ushort4 o;
    o.x = f2bf(v.x); o.y = f2bf(v.y); o.z = f2bf(v.z); o.w = f2bf(v.w);
    reinterpret_cast<ushort4*>(xbf)[i] = o;
}

// ---------------------------------------------------------------- router
// one wave per token
__global__ __launch_bounds__(256) void router_kernel(const float* __restrict__ x,
                                                     const float* __restrict__ Wg,
                                                     const float* __restrict__ bg,
                                                     float* __restrict__ wts,     // [T][8]
                                                     float* __restrict__ probs,   // [T][8]
                                                     float* __restrict__ ent,     // [T]
                                                     float* __restrict__ act_out) // [T] (float)
{
    int wave = threadIdx.x >> 6;
    int lane = threadIdx.x & 63;
    int t = blockIdx.x * 4 + wave;

    float acc[8];
#pragma unroll
    for (int e = 0; e < 8; ++e) acc[e] = 0.f;

    const float* xrow = x + (size_t)t * D_MODEL;
    for (int d = lane; d < D_MODEL; d += 64) {
        float xv = xrow[d];
        const float4* wg = reinterpret_cast<const float4*>(Wg + (size_t)d * 8);
        float4 a = wg[0], b = wg[1];
        acc[0] += xv * a.x; acc[1] += xv * a.y; acc[2] += xv * a.z; acc[3] += xv * a.w;
        acc[4] += xv * b.x; acc[5] += xv * b.y; acc[6] += xv * b.z; acc[7] += xv * b.w;
    }
#pragma unroll
    for (int e = 0; e < 8; ++e) {
#pragma unroll
        for (int off = 32; off > 0; off >>= 1) acc[e] += __shfl_xor(acc[e], off);
    }

    if (lane == 0) {
        float l[8], p[8];
        float m = -1e30f;
#pragma unroll
        for (int e = 0; e < 8; ++e) { l[e] = acc[e] + bg[e]; m = fmaxf(m, l[e]); }
        float s = 0.f;
#pragma unroll
        for (int e = 0; e < 8; ++e) { p[e] = expf(l[e] - m); s += p[e]; }
        float inv = 1.f / s;
#pragma unroll
        for (int e = 0; e < 8; ++e) p[e] *= inv;

        // stable descending sort of 8
        int idx[8]; float sp[8];
#pragma unroll
        for (int e = 0; e < 8; ++e) { idx[e] = e; sp[e] = p[e]; }
        for (int i = 0; i < 8; ++i) {
            int best = i;
            for (int j = i + 1; j < 8; ++j) if (sp[j] > sp[best]) best = j;
            float tv = sp[i]; sp[i] = sp[best]; sp[best] = tv;
            int ti = idx[i]; idx[i] = idx[best]; idx[best] = ti;
        }
        // exclusive cumsum threshold
        float cum = 0.f, asum = 0.f, ap[8];
        int cnt = 0;
        for (int i = 0; i < 8; ++i) {
            int active = (i == 0) || (cum < THRESH);
            cum += sp[i];
            ap[i] = active ? sp[i] : 0.f;
            asum += ap[i];
            cnt += active;
        }
        float rinv = 1.f / (asum + EPS_R);
        float w[8];
        for (int i = 0; i < 8; ++i) w[idx[i]] = ap[i] * rinv;

        float* wrow = wts + (size_t)t * 8;
        float* prow = probs + (size_t)t * 8;
        float e_sum = 0.f;
#pragma unroll
        for (int e = 0; e < 8; ++e) {
            wrow[e] = w[e];
            prow[e] = p[e];
            e_sum -= p[e] * logf(p[e] + EPS_R);
        }
        ent[t] = e_sum;
        act_out[t] = (float)cnt;
    }
}

// ---------------------------------------------------------------- loss reduce (single block, deterministic)
__global__ __launch_bounds__(256) void loss_kernel(const float* __restrict__ wts,
                                                   const float* __restrict__ probs,
                                                   const float* __restrict__ ent,
                                                   float* __restrict__ out_scalars) // [2]
{
    int tid = threadIdx.x;
    float fsum[8], psum[8], es = 0.f;
#pragma unroll
    for (int e = 0; e < 8; ++e) { fsum[e] = 0.f; psum[e] = 0.f; }
    for (int t = tid; t < TOKENS; t += 256) {
        const float* wrow = wts + (size_t)t * 8;
        const float* prow = probs + (size_t)t * 8;
#pragma unroll
        for (int e = 0; e < 8; ++e) {
            fsum[e] += (wrow[e] > 0.f) ? 1.f : 0.f;
            psum[e] += prow[e];
        }
        es += ent[t];
    }
    __shared__ float red[256];
    __shared__ float tot[17];
    for (int q = 0; q < 17; ++q) {
        float v = (q < 8) ? fsum[q] : ((q < 16) ? psum[q - 8] : es);
        red[tid] = v; __syncthreads();
        for (int s = 128; s > 0; s >>= 1) {
            if (tid < s) red[tid] += red[tid + s];
            __syncthreads();
        }
        if (tid == 0) tot[q] = red[0];
        __syncthreads();
    }
    if (tid == 0) {
        const float invT = 1.f / (float)TOKENS;
        float lb = 0.f;
        for (int e = 0; e < 8; ++e) lb += (tot[e] * invT) * (tot[8 + e] * invT);
        out_scalars[0] = 8.f * lb;
        out_scalars[1] = tot[16] * invT;
    }
}

// ---------------------------------------------------------------- GEMM1: g = silu(x@W1+b1)*(x@W3+b3)
// block 256 (4 waves, 2x2), tile 128x64, BK=32
__global__ __launch_bounds__(256) void gemm1_kernel(const ushort_t* __restrict__ xbf,
                                                    const float* __restrict__ W1e,
                                                    const float* __restrict__ b1e,
                                                    const float* __restrict__ W3e,
                                                    const float* __restrict__ b3e,
                                                    ushort_t* __restrict__ g) {
    __shared__ ushort_t sX[128][40];
    __shared__ ushort_t sW1[64][40];
    __shared__ ushort_t sW3[64][40];

    const int tid = threadIdx.x;
    const int lane = tid & 63;
    const int wave = tid >> 6;
    const int wr = wave >> 1, wc = wave & 1;
    const int m0 = blockIdx.y * 128;
    const int n0 = blockIdx.x * 64;

    f32x4 acc1[4][2], acc3[4][2];
#pragma unroll
    for (int i = 0; i < 4; ++i)
#pragma unroll
        for (int j = 0; j < 2; ++j) { acc1[i][j] = (f32x4)0.f; acc3[i][j] = (f32x4)0.f; }

    const int xr = tid >> 1;               // 0..127
    const int xc = (tid & 1) * 16;         // 0 or 16
    const int wrw = tid >> 3;              // 0..31 (K row)
    const int wcc = (tid & 7) * 8;         // 0..56

    for (int kk = 0; kk < D_MODEL; kk += 32) {
        // stage X
        const uint4* xs = reinterpret_cast<const uint4*>(xbf + (size_t)(m0 + xr) * D_MODEL + kk + xc);
        uint4 v0 = xs[0], v1 = xs[1];
        *reinterpret_cast<uint4*>(&sX[xr][xc]) = v0;
        *reinterpret_cast<uint4*>(&sX[xr][xc + 8]) = v1;
        // stage W1 / W3 (fp32 -> bf16, transposed into LDS)
        {
            const float4* w1s = reinterpret_cast<const float4*>(W1e + (size_t)(kk + wrw) * D_FF + n0 + wcc);
            float4 a = w1s[0], b = w1s[1];
            sW1[wcc + 0][wrw] = f2bf(a.x); sW1[wcc + 1][wrw] = f2bf(a.y);
            sW1[wcc + 2][wrw] = f2bf(a.z); sW1[wcc + 3][wrw] = f2bf(a.w);
            sW1[wcc + 4][wrw] = f2bf(b.x); sW1[wcc + 5][wrw] = f2bf(b.y);
            sW1[wcc + 6][wrw] = f2bf(b.z); sW1[wcc + 7][wrw] = f2bf(b.w);
            const float4* w3s = reinterpret_cast<const float4*>(W3e + (size_t)(kk + wrw) * D_FF + n0 + wcc);
            float4 c = w3s[0], d = w3s[1];
            sW3[wcc + 0][wrw] = f2bf(c.x); sW3[wcc + 1][wrw] = f2bf(c.y);
            sW3[wcc + 2][wrw] = f2bf(c.z); sW3[wcc + 3][wrw] = f2bf(c.w);
            sW3[wcc + 4][wrw] = f2bf(d.x); sW3[wcc + 5][wrw] = f2bf(d.y);
            sW3[wcc + 6][wrw] = f2bf(d.z); sW3[wcc + 7][wrw] = f2bf(d.w);
        }
        __syncthreads();

        bf16x8 a[4], u1[2], u3[2];
#pragma unroll
        for (int fm = 0; fm < 4; ++fm)
            a[fm] = *reinterpret_cast<const bf16x8*>(&sX[wr * 64 + fm * 16 + (lane & 15)][(lane >> 4) * 8]);
#pragma unroll
        for (int fn = 0; fn < 2; ++fn) {
            u1[fn] = *reinterpret_cast<const bf16x8*>(&sW1[wc * 32 + fn * 16 + (lane & 15)][(lane >> 4) * 8]);
            u3[fn] = *reinterpret_cast<const bf16x8*>(&sW3[wc * 32 + fn * 16 + (lane & 15)][(lane >> 4) * 8]);
        }
#pragma unroll
        for (int fm = 0; fm < 4; ++fm)
#pragma unroll
            for (int fn = 0; fn < 2; ++fn) {
                acc1[fm][fn] = __builtin_amdgcn_mfma_f32_16x16x32_bf16(a[fm], u1[fn], acc1[fm][fn], 0, 0, 0);
                acc3[fm][fn] = __builtin_amdgcn_mfma_f32_16x16x32_bf16(a[fm], u3[fn], acc3[fm][fn], 0, 0, 0);
            }
        __syncthreads();
    }

    // epilogue: SwiGLU -> bf16 g
#pragma unroll
    for (int fm = 0; fm < 4; ++fm) {
#pragma unroll
        for (int fn = 0; fn < 2; ++fn) {
            int col = n0 + wc * 32 + fn * 16 + (lane & 15);
            float bb1 = b1e[col];
            float bb3 = b3e[col];
#pragma unroll
            for (int r = 0; r < 4; ++r) {
                int row = m0 + wr * 64 + fm * 16 + (lane >> 4) * 4 + r;
                float h1 = acc1[fm][fn][r] + bb1;
                float h3 = acc3[fm][fn][r] + bb3;
                float gv = (h1 / (1.f + expf(-h1))) * h3;
                g[(size_t)row * D_FF + col] = f2bf(gv);
            }
        }
    }
}

// ---------------------------------------------------------------- GEMM2: out += w[t,e] * (g@W2 + b2)
__global__ __launch_bounds__(256) void gemm2_kernel(const ushort_t* __restrict__ g,
                                                    const float* __restrict__ W2e,
                                                    const float* __restrict__ b2e,
                                                    const float* __restrict__ wts,
                                                    int expert, int first,
                                                    float* __restrict__ out) {
    __shared__ ushort_t sA[128][40];
    __shared__ ushort_t sB[64][40];

    const int tid = threadIdx.x;
    const int lane = tid & 63;
    const int wave = tid >> 6;
    const int wr = wave >> 1, wc = wave & 1;
    const int m0 = blockIdx.y * 128;
    const int n0 = blockIdx.x * 64;

    f32x4 acc[4][2];
#pragma unroll
    for (int i = 0; i < 4; ++i)
#pragma unroll
        for (int j = 0; j < 2; ++j) acc[i][j] = (f32x4)0.f;

    const int xr = tid >> 1;
    const int xc = (tid & 1) * 16;
    const int wrw = tid >> 3;
    const int wcc = (tid & 7) * 8;

    for (int kk = 0; kk < D_FF; kk += 32) {
        const uint4* as = reinterpret_cast<const uint4*>(g + (size_t)(m0 + xr) * D_FF + kk + xc);
        uint4 v0 = as[0], v1 = as[1];
        *reinterpret_cast<uint4*>(&sA[xr][xc]) = v0;
        *reinterpret_cast<uint4*>(&sA[xr][xc + 8]) = v1;
        {
            const float4* bs = reinterpret_cast<const float4*>(W2e + (size_t)(kk + wrw) * D_MODEL + n0 + wcc);
            float4 a = bs[0], b = bs[1];
            sB[wcc + 0][wrw] = f2bf(a.x); sB[wcc + 1][wrw] = f2bf(a.y);
            sB[wcc + 2][wrw] = f2bf(a.z); sB[wcc + 3][wrw] = f2bf(a.w);
            sB[wcc + 4][wrw] = f2bf(b.x); sB[wcc + 5][wrw] = f2bf(b.y);
            sB[wcc + 6][wrw] = f2bf(b.z); sB[wcc + 7][wrw] = f2bf(b.w);
        }
        __syncthreads();

        bf16x8 a[4], b[2];
#pragma unroll
        for (int fm = 0; fm < 4; ++fm)
            a[fm] = *reinterpret_cast<const bf16x8*>(&sA[wr * 64 + fm * 16 + (lane & 15)][(lane >> 4) * 8]);
#pragma unroll
        for (int fn = 0; fn < 2; ++fn)
            b[fn] = *reinterpret_cast<const bf16x8*>(&sB[wc * 32 + fn * 16 + (lane & 15)][(lane >> 4) * 8]);
#pragma unroll
        for (int fm = 0; fm < 4; ++fm)
#pragma unroll
            for (int fn = 0; fn < 2; ++fn)
                acc[fm][fn] = __builtin_amdgcn_mfma_f32_16x16x32_bf16(a[fm], b[fn], acc[fm][fn], 0, 0, 0);
        __syncthreads();
    }

#pragma unroll
    for (int fm = 0; fm < 4; ++fm) {
#pragma unroll
        for (int fn = 0; fn < 2; ++fn) {
            int col = n0 + wc * 32 + fn * 16 + (lane & 15);
            float bb2 = b2e[col];
#pragma unroll
            for (int r = 0; r < 4; ++r) {
                int row = m0 + wr * 64 + fm * 16 + (lane >> 4) * 4 + r;
                float val = acc[fm][fn][r] + bb2;
                float w = wts[(size_t)row * 8 + expert];
                float* o = out + (size_t)row * D_MODEL + col;
                if (first) *o = w * val;
                else       *o += w * val;
            }
        }
    }
}

// ---------------------------------------------------------------- launch
extern "C" void kernel_launch(void* const* d_in, const int* in_sizes, int n_in,
                              void* d_out, int out_size, void* d_ws, size_t ws_size,
                              hipStream_t stream) {
    const float* x  = (const float*)d_in[0];
    const float* Wg = (const float*)d_in[1];
    const float* bg = (const float*)d_in[2];
    const float* W1 = (const float*)d_in[3];
    const float* b1 = (const float*)d_in[4];
    const float* W3 = (const float*)d_in[5];
    const float* b3 = (const float*)d_in[6];
    const float* W2 = (const float*)d_in[7];
    const float* b2 = (const float*)d_in[8];
    float* out = (float*)d_out;

    char* wsb = (char*)d_ws;
    ushort_t* xbf  = (ushort_t*)(wsb);                       // 4 MiB
    float*    wts  = (float*)(wsb + 4194304);                // 64 KiB
    float*    probs= (float*)(wsb + 4194304 + 65536);        // 64 KiB
    float*    ent  = (float*)(wsb + 4194304 + 131072);       // 8 KiB
    ushort_t* gbuf = (ushort_t*)(wsb + 4194304 + 139264);    // 16 MiB

    float* out_scalars = out + FINAL_SIZE;        // [2]
    float* out_act     = out + FINAL_SIZE + 2;    // [TOKENS]

    convert_x_kernel<<<TOKENS * D_MODEL / (256 * 4), 256, 0, stream>>>(x, xbf);
    router_kernel<<<TOKENS / 4, 256, 0, stream>>>(x, Wg, bg, wts, probs, ent, out_act);
    loss_kernel<<<1, 256, 0, stream>>>(wts, probs, ent, out_scalars);

    dim3 g1(D_FF / 64, TOKENS / 128);   // 64 x 16
    dim3 g2(D_MODEL / 64, TOKENS / 128); // 16 x 16
    for (int e = 0; e < N_EXP; ++e) {
        const float* W1e = W1 + (size_t)e * D_MODEL * D_FF;
        const float* b1e = b1 + (size_t)e * D_FF;
        const float* W3e = W3 + (size_t)e * D_MODEL * D_FF;
        const float* b3e = b3 + (size_t)e * D_FF;
        const float* W2e = W2 + (size_t)e * D_FF * D_MODEL;
        const float* b2e = b2 + (size_t)e * D_MODEL;
        gemm1_kernel<<<g1, 256, 0, stream>>>(xbf, W1e, b1e, W3e, b3e, gbuf);
        gemm2_kernel<<<g2, 256, 0, stream>>>(gbuf, W2e, b2e, wts, e, (e == 0) ? 1 : 0, out);
    }
}

// Round 2
// 701.005 us; speedup vs baseline: 2.8172x; 2.8172x over previous
//
#include <hip/hip_runtime.h>
#include <hip/hip_bf16.h>
#include <math.h>

// Problem constants
#define D_MODEL 1024
#define D_FF    4096
#define N_EXP   8
#define TOKENS  2048          // 2 * 1024
#define THRESH  0.8f
#define EPS_R   1e-6f

#define FINAL_SIZE (TOKENS * D_MODEL)   // 2097152

typedef unsigned short ushort_t;
typedef __attribute__((ext_vector_type(4))) float f32x4;
typedef __attribute__((ext_vector_type(8))) short bf16x8;

__device__ __forceinline__ unsigned short f2bf(float f) {
    unsigned u = __builtin_bit_cast(unsigned, f);
    unsigned r = (u + 0x7FFFu + ((u >> 16) & 1u)) >> 16;
    return (unsigned short)r;
}

// async global->LDS, 16B per lane; lds base must be wave-uniform
template <typename T>
__device__ __forceinline__ void gload16(const T* gsrc, T* ldst) {
    __builtin_amdgcn_global_load_lds((const __attribute__((address_space(1))) unsigned int*)gsrc,
                                     (__attribute__((address_space(3))) unsigned int*)ldst,
                                     16, 0, 0);
}

// ---------------------------------------------------------------- convert x fp32 -> bf16
__global__ __launch_bounds__(256) void convert_x_kernel(const float* __restrict__ x,
                                                        ushort_t* __restrict__ xbf) {
    int i = blockIdx.x * 256 + threadIdx.x;   // each handles 4 floats
    const float4 v = reinterpret_cast<const float4*>(x)[i];
    ushort4 o;
    o.x = f2bf(v.x); o.y = f2bf(v.y); o.z = f2bf(v.z); o.w = f2bf(v.w);
    reinterpret_cast<ushort4*>(xbf)[i] = o;
}

// ---------------------------------------------------------------- weight transpose+convert
// in: [K][N] fp32 (expert e at e*K*N), out: [N][K] bf16 (expert e at e*K*N)
__global__ __launch_bounds__(256) void wconv_kernel(const float* __restrict__ in,
                                                    ushort_t* __restrict__ out,
                                                    int K, int N) {
    __shared__ float sT[32][33];
    const int e = blockIdx.z;
    const float* src = in + (size_t)e * K * N;
    ushort_t* dst = out + (size_t)e * K * N;
    const int k0 = blockIdx.y * 32, n0 = blockIdx.x * 32;
    const int r = threadIdx.x >> 3;          // 0..31
    const int c4 = (threadIdx.x & 7) * 4;    // 0..28
    float4 v = *reinterpret_cast<const float4*>(src + (size_t)(k0 + r) * N + n0 + c4);
    sT[r][c4 + 0] = v.x; sT[r][c4 + 1] = v.y; sT[r][c4 + 2] = v.z; sT[r][c4 + 3] = v.w;
    __syncthreads();
    ushort4 o;
    o.x = f2bf(sT[c4 + 0][r]); o.y = f2bf(sT[c4 + 1][r]);
    o.z = f2bf(sT[c4 + 2][r]); o.w = f2bf(sT[c4 + 3][r]);
    *reinterpret_cast<ushort4*>(dst + (size_t)(n0 + r) * K + k0 + c4) = o;
}

// ---------------------------------------------------------------- router (one wave per token)
__global__ __launch_bounds__(256) void router_kernel(const float* __restrict__ x,
                                                     const float* __restrict__ Wg,
                                                     const float* __restrict__ bg,
                                                     float* __restrict__ wts,     // [T][8]
                                                     float* __restrict__ probs,   // [T][8]
                                                     float* __restrict__ ent,     // [T]
                                                     float* __restrict__ act_out) // [T]
{
    int wave = threadIdx.x >> 6;
    int lane = threadIdx.x & 63;
    int t = blockIdx.x * 4 + wave;

    float acc[8];
#pragma unroll
    for (int e = 0; e < 8; ++e) acc[e] = 0.f;

    const float* xrow = x + (size_t)t * D_MODEL;
    for (int d = lane; d < D_MODEL; d += 64) {
        float xv = xrow[d];
        const float4* wg = reinterpret_cast<const float4*>(Wg + (size_t)d * 8);
        float4 a = wg[0], b = wg[1];
        acc[0] += xv * a.x; acc[1] += xv * a.y; acc[2] += xv * a.z; acc[3] += xv * a.w;
        acc[4] += xv * b.x; acc[5] += xv * b.y; acc[6] += xv * b.z; acc[7] += xv * b.w;
    }
#pragma unroll
    for (int e = 0; e < 8; ++e) {
#pragma unroll
        for (int off = 32; off > 0; off >>= 1) acc[e] += __shfl_xor(acc[e], off);
    }

    if (lane == 0) {
        float l[8], p[8];
        float m = -1e30f;
#pragma unroll
        for (int e = 0; e < 8; ++e) { l[e] = acc[e] + bg[e]; m = fmaxf(m, l[e]); }
        float s = 0.f;
#pragma unroll
        for (int e = 0; e < 8; ++e) { p[e] = expf(l[e] - m); s += p[e]; }
        float inv = 1.f / s;
#pragma unroll
        for (int e = 0; e < 8; ++e) p[e] *= inv;

        int idx[8]; float sp[8];
#pragma unroll
        for (int e = 0; e < 8; ++e) { idx[e] = e; sp[e] = p[e]; }
        for (int i = 0; i < 8; ++i) {
            int best = i;
            for (int j = i + 1; j < 8; ++j) if (sp[j] > sp[best]) best = j;
            float tv = sp[i]; sp[i] = sp[best]; sp[best] = tv;
            int ti = idx[i]; idx[i] = idx[best]; idx[best] = ti;
        }
        float cum = 0.f, asum = 0.f, ap[8];
        int cnt = 0;
        for (int i = 0; i < 8; ++i) {
            int active = (i == 0) || (cum < THRESH);
            cum += sp[i];
            ap[i] = active ? sp[i] : 0.f;
            asum += ap[i];
            cnt += active;
        }
        float rinv = 1.f / (asum + EPS_R);
        float w[8];
        for (int i = 0; i < 8; ++i) w[idx[i]] = ap[i] * rinv;

        float* wrow = wts + (size_t)t * 8;
        float* prow = probs + (size_t)t * 8;
        float e_sum = 0.f;
#pragma unroll
        for (int e = 0; e < 8; ++e) {
            wrow[e] = w[e];
            prow[e] = p[e];
            e_sum -= p[e] * logf(p[e] + EPS_R);
        }
        ent[t] = e_sum;
        act_out[t] = (float)cnt;
    }
}

// ---------------------------------------------------------------- loss reduce (single block, deterministic)
__global__ __launch_bounds__(256) void loss_kernel(const float* __restrict__ wts,
                                                   const float* __restrict__ probs,
                                                   const float* __restrict__ ent,
                                                   float* __restrict__ out_scalars) // [2]
{
    int tid = threadIdx.x;
    float fsum[8], psum[8], es = 0.f;
#pragma unroll
    for (int e = 0; e < 8; ++e) { fsum[e] = 0.f; psum[e] = 0.f; }
    for (int t = tid; t < TOKENS; t += 256) {
        const float* wrow = wts + (size_t)t * 8;
        const float* prow = probs + (size_t)t * 8;
#pragma unroll
        for (int e = 0; e < 8; ++e) {
            fsum[e] += (wrow[e] > 0.f) ? 1.f : 0.f;
            psum[e] += prow[e];
        }
        es += ent[t];
    }
    __shared__ float red[256];
    __shared__ float tot[17];
    for (int q = 0; q < 17; ++q) {
        float v = (q < 8) ? fsum[q] : ((q < 16) ? psum[q - 8] : es);
        red[tid] = v; __syncthreads();
        for (int s = 128; s > 0; s >>= 1) {
            if (tid < s) red[tid] += red[tid + s];
            __syncthreads();
        }
        if (tid == 0) tot[q] = red[0];
        __syncthreads();
    }
    if (tid == 0) {
        const float invT = 1.f / (float)TOKENS;
        float lb = 0.f;
        for (int e = 0; e < 8; ++e) lb += (tot[e] * invT) * (tot[8 + e] * invT);
        out_scalars[0] = 8.f * lb;
        out_scalars[1] = tot[16] * invT;
    }
}

// ---------------------------------------------------------------- GEMM1: g = silu(x@W1+b1)*(x@W3+b3)
// tile 128(M) x 64(N), BK=64, 4 waves (2x2), per-wave 64x32, dual B (W1,W3)
__global__ __launch_bounds__(256, 2) void gemm1_kernel(const ushort_t* __restrict__ xbf, // [T][1024]
                                                       const ushort_t* __restrict__ w1t, // [GS][4096][1024]
                                                       const ushort_t* __restrict__ w3t,
                                                       const float* __restrict__ b1,     // [E][4096] global
                                                       const float* __restrict__ b3,
                                                       ushort_t* __restrict__ g,         // [GS][T][4096]
                                                       int gbase) {
    __shared__ ushort_t sA[128 * 64];
    __shared__ ushort_t sB1[64 * 64];
    __shared__ ushort_t sB3[64 * 64];

    const int tid = threadIdx.x;
    const int lane = tid & 63;
    const int wave = tid >> 6;
    const int wr = wave >> 1, wc = wave & 1;
    const int z = blockIdx.z;
    const int ge = gbase + z;
    const int m0 = blockIdx.y * 128;
    const int n0 = blockIdx.x * 64;

    const ushort_t* w1e = w1t + (size_t)z * D_FF * D_MODEL;
    const ushort_t* w3e = w3t + (size_t)z * D_FF * D_MODEL;

    f32x4 acc1[4][2], acc3[4][2];
#pragma unroll
    for (int i = 0; i < 4; ++i)
#pragma unroll
        for (int j = 0; j < 2; ++j) { acc1[i][j] = (f32x4)0.f; acc3[i][j] = (f32x4)0.f; }

    const int srow = tid >> 3;        // 0..31
    const int scol = (tid & 7) * 8;   // bf16 col within 64-wide K slice

    for (int kk = 0; kk < D_MODEL; kk += 64) {
        // A: 128x64 bf16 = 16 KB = 4 rounds of (256 lanes x 16B)
#pragma unroll
        for (int r = 0; r < 4; ++r)
            gload16(xbf + (size_t)(m0 + srow + r * 32) * D_MODEL + kk + scol,
                    sA + r * 2048 + wave * 512);
        // B1/B3: 64x64 = 8 KB = 2 rounds each
#pragma unroll
        for (int r = 0; r < 2; ++r) {
            gload16(w1e + (size_t)(n0 + srow + r * 32) * D_MODEL + kk + scol,
                    sB1 + r * 2048 + wave * 512);
            gload16(w3e + (size_t)(n0 + srow + r * 32) * D_MODEL + kk + scol,
                    sB3 + r * 2048 + wave * 512);
        }
        __syncthreads();   // compiler emits vmcnt(0) drain + barrier

#pragma unroll
        for (int ks = 0; ks < 2; ++ks) {
            const int ko = ks * 32 + (lane >> 4) * 8;
            bf16x8 a[4], u1[2], u3[2];
#pragma unroll
            for (int fm = 0; fm < 4; ++fm)
                a[fm] = *reinterpret_cast<const bf16x8*>(&sA[(wr * 64 + fm * 16 + (lane & 15)) * 64 + ko]);
#pragma unroll
            for (int fn = 0; fn < 2; ++fn) {
                u1[fn] = *reinterpret_cast<const bf16x8*>(&sB1[(wc * 32 + fn * 16 + (lane & 15)) * 64 + ko]);
                u3[fn] = *reinterpret_cast<const bf16x8*>(&sB3[(wc * 32 + fn * 16 + (lane & 15)) * 64 + ko]);
            }
#pragma unroll
            for (int fm = 0; fm < 4; ++fm)
#pragma unroll
                for (int fn = 0; fn < 2; ++fn) {
                    acc1[fm][fn] = __builtin_amdgcn_mfma_f32_16x16x32_bf16(a[fm], u1[fn], acc1[fm][fn], 0, 0, 0);
                    acc3[fm][fn] = __builtin_amdgcn_mfma_f32_16x16x32_bf16(a[fm], u3[fn], acc3[fm][fn], 0, 0, 0);
                }
        }
        __syncthreads();
    }

    // epilogue: SwiGLU -> bf16 g
    ushort_t* ge_out = g + (size_t)z * TOKENS * D_FF;
#pragma unroll
    for (int fn = 0; fn < 2; ++fn) {
        int col = n0 + wc * 32 + fn * 16 + (lane & 15);
        float bb1 = b1[(size_t)ge * D_FF + col];
        float bb3 = b3[(size_t)ge * D_FF + col];
#pragma unroll
        for (int fm = 0; fm < 4; ++fm) {
#pragma unroll
            for (int r = 0; r < 4; ++r) {
                int row = m0 + wr * 64 + fm * 16 + (lane >> 4) * 4 + r;
                float h1 = acc1[fm][fn][r] + bb1;
                float h3 = acc3[fm][fn][r] + bb3;
                float gv = (h1 / (1.f + expf(-h1))) * h3;
                ge_out[(size_t)row * D_FF + col] = f2bf(gv);
            }
        }
    }
}

// ---------------------------------------------------------------- GEMM2: part[e] = w[t,e] * (g@W2 + b2)
// tile 128(M) x 64(N), BK=64, 4 waves (2x2), per-wave 64x32
__global__ __launch_bounds__(256, 2) void gemm2_kernel(const ushort_t* __restrict__ g,   // [GS][T][4096]
                                                       const ushort_t* __restrict__ w2t, // [GS][1024][4096]
                                                       const float* __restrict__ b2,     // [E][1024] global
                                                       const float* __restrict__ wts,    // [T][8]
                                                       float* __restrict__ part,         // [GS][T][1024]
                                                       int gbase) {
    __shared__ ushort_t sA[128 * 64];
    __shared__ ushort_t sB[64 * 64];

    const int tid = threadIdx.x;
    const int lane = tid & 63;
    const int wave = tid >> 6;
    const int wr = wave >> 1, wc = wave & 1;
    const int z = blockIdx.z;
    const int ge = gbase + z;
    const int m0 = blockIdx.y * 128;
    const int n0 = blockIdx.x * 64;

    const ushort_t* ga = g + (size_t)z * TOKENS * D_FF;
    const ushort_t* w2e = w2t + (size_t)z * D_MODEL * D_FF;

    f32x4 acc[4][2];
#pragma unroll
    for (int i = 0; i < 4; ++i)
#pragma unroll
        for (int j = 0; j < 2; ++j) acc[i][j] = (f32x4)0.f;

    const int srow = tid >> 3;
    const int scol = (tid & 7) * 8;

    for (int kk = 0; kk < D_FF; kk += 64) {
#pragma unroll
        for (int r = 0; r < 4; ++r)
            gload16(ga + (size_t)(m0 + srow + r * 32) * D_FF + kk + scol,
                    sA + r * 2048 + wave * 512);
#pragma unroll
        for (int r = 0; r < 2; ++r)
            gload16(w2e + (size_t)(n0 + srow + r * 32) * D_FF + kk + scol,
                    sB + r * 2048 + wave * 512);
        __syncthreads();

#pragma unroll
        for (int ks = 0; ks < 2; ++ks) {
            const int ko = ks * 32 + (lane >> 4) * 8;
            bf16x8 a[4], b[2];
#pragma unroll
            for (int fm = 0; fm < 4; ++fm)
                a[fm] = *reinterpret_cast<const bf16x8*>(&sA[(wr * 64 + fm * 16 + (lane & 15)) * 64 + ko]);
#pragma unroll
            for (int fn = 0; fn < 2; ++fn)
                b[fn] = *reinterpret_cast<const bf16x8*>(&sB[(wc * 32 + fn * 16 + (lane & 15)) * 64 + ko]);
#pragma unroll
            for (int fm = 0; fm < 4; ++fm)
#pragma unroll
                for (int fn = 0; fn < 2; ++fn)
                    acc[fm][fn] = __builtin_amdgcn_mfma_f32_16x16x32_bf16(a[fm], b[fn], acc[fm][fn], 0, 0, 0);
        }
        __syncthreads();
    }

    float* pe = part + (size_t)z * TOKENS * D_MODEL;
    float bb2[2];
#pragma unroll
    for (int fn = 0; fn < 2; ++fn)
        bb2[fn] = b2[(size_t)ge * D_MODEL + n0 + wc * 32 + fn * 16 + (lane & 15)];
#pragma unroll
    for (int fm = 0; fm < 4; ++fm) {
#pragma unroll
        for (int r = 0; r < 4; ++r) {
            int row = m0 + wr * 64 + fm * 16 + (lane >> 4) * 4 + r;
            float w = wts[(size_t)row * 8 + ge];
#pragma unroll
            for (int fn = 0; fn < 2; ++fn) {
                int col = n0 + wc * 32 + fn * 16 + (lane & 15);
                pe[(size_t)row * D_MODEL + col] = (acc[fm][fn][r] + bb2[fn]) * w;
            }
        }
    }
}

// ---------------------------------------------------------------- deterministic partial reduce
__global__ __launch_bounds__(256) void reduce_kernel(const float* __restrict__ part,
                                                     float* __restrict__ out,
                                                     int nE, int first) {
    size_t i = (size_t)blockIdx.x * 256 + threadIdx.x;   // float4 index
    const float4* p = reinterpret_cast<const float4*>(part);
    float4 s = p[i];
    for (int e = 1; e < nE; ++e) {
        float4 v = p[i + (size_t)e * (FINAL_SIZE / 4)];
        s.x += v.x; s.y += v.y; s.z += v.z; s.w += v.w;
    }
    float4* o = reinterpret_cast<float4*>(out);
    if (first) o[i] = s;
    else {
        float4 c = o[i];
        c.x += s.x; c.y += s.y; c.z += s.z; c.w += s.w;
        o[i] = c;
    }
}

// ---------------------------------------------------------------- launch
extern "C" void kernel_launch(void* const* d_in, const int* in_sizes, int n_in,
                              void* d_out, int out_size, void* d_ws, size_t ws_size,
                              hipStream_t stream) {
    const float* x  = (const float*)d_in[0];
    const float* Wg = (const float*)d_in[1];
    const float* bg = (const float*)d_in[2];
    const float* W1 = (const float*)d_in[3];
    const float* b1 = (const float*)d_in[4];
    const float* W3 = (const float*)d_in[5];
    const float* b3 = (const float*)d_in[6];
    const float* W2 = (const float*)d_in[7];
    const float* b2 = (const float*)d_in[8];
    float* out = (float*)d_out;

    char* wsb = (char*)d_ws;
    ushort_t* xbf  = (ushort_t*)(wsb);                       // 4 MiB
    float*    wts  = (float*)(wsb + (4u << 20));             // 64 KiB
    float*    probs= (float*)(wsb + (4u << 20) + 65536);     // 64 KiB
    float*    ent  = (float*)(wsb + (4u << 20) + 131072);    // 8 KiB

    // adaptive expert-group size vs workspace capacity (48 MiB / expert)
    const size_t PER_E = (size_t)48 << 20;
    const size_t BASE  = (size_t)8 << 20;
    int GS = 4;
    if (ws_size < BASE + 4 * PER_E) GS = 2;
    if (ws_size < BASE + 2 * PER_E) GS = 1;

    char* big = wsb + BASE;
    const size_t W_SZ = (size_t)GS * ((size_t)D_FF * D_MODEL * 2);   // 8 MiB per expert
    ushort_t* w1t  = (ushort_t*)big;
    ushort_t* w3t  = (ushort_t*)(big + W_SZ);
    ushort_t* w2t  = (ushort_t*)(big + 2 * W_SZ);
    ushort_t* gbuf = (ushort_t*)(big + 3 * W_SZ);
    float*    part = (float*)(big + 3 * W_SZ + (size_t)GS * ((size_t)TOKENS * D_FF * 2));

    float* out_scalars = out + FINAL_SIZE;        // [2]
    float* out_act     = out + FINAL_SIZE + 2;    // [TOKENS]

    convert_x_kernel<<<TOKENS * D_MODEL / (256 * 4), 256, 0, stream>>>(x, xbf);
    router_kernel<<<TOKENS / 4, 256, 0, stream>>>(x, Wg, bg, wts, probs, ent, out_act);
    loss_kernel<<<1, 256, 0, stream>>>(wts, probs, ent, out_scalars);

    for (int g0 = 0; g0 < N_EXP; g0 += GS) {
        // weight convert+transpose for this expert group
        wconv_kernel<<<dim3(D_FF / 32, D_MODEL / 32, GS), 256, 0, stream>>>(
            W1 + (size_t)g0 * D_MODEL * D_FF, w1t, D_MODEL, D_FF);
        wconv_kernel<<<dim3(D_FF / 32, D_MODEL / 32, GS), 256, 0, stream>>>(
            W3 + (size_t)g0 * D_MODEL * D_FF, w3t, D_MODEL, D_FF);
        wconv_kernel<<<dim3(D_MODEL / 32, D_FF / 32, GS), 256, 0, stream>>>(
            W2 + (size_t)g0 * D_FF * D_MODEL, w2t, D_FF, D_MODEL);

        gemm1_kernel<<<dim3(D_FF / 64, TOKENS / 128, GS), 256, 0, stream>>>(
            xbf, w1t, w3t, b1, b3, gbuf, g0);
        gemm2_kernel<<<dim3(D_MODEL / 64, TOKENS / 128, GS), 256, 0, stream>>>(
            gbuf, w2t, b2, wts, part, g0);
        reduce_kernel<<<FINAL_SIZE / 4 / 256, 256, 0, stream>>>(part, out, GS, g0 == 0 ? 1 : 0);
    }
}

// Round 3
// 609.838 us; speedup vs baseline: 3.2383x; 1.1495x over previous
//
#include <hip/hip_runtime.h>
#include <hip/hip_bf16.h>
#include <math.h>

// Problem constants
#define D_MODEL 1024
#define D_FF    4096
#define N_EXP   8
#define TOKENS  2048          // 2 * 1024
#define THRESH  0.8f
#define EPS_R   1e-6f

#define FINAL_SIZE (TOKENS * D_MODEL)   // 2097152

typedef unsigned short ushort_t;
typedef __attribute__((ext_vector_type(4))) float f32x4;
typedef __attribute__((ext_vector_type(8))) short bf16x8;

__device__ __forceinline__ unsigned short f2bf(float f) {
    unsigned u = __builtin_bit_cast(unsigned, f);
    unsigned r = (u + 0x7FFFu + ((u >> 16) & 1u)) >> 16;
    return (unsigned short)r;
}

// async global->LDS, 16B per lane; lds base must be wave-uniform (+lane*16 implicit)
template <typename T>
__device__ __forceinline__ void gload16(const T* gsrc, T* ldst) {
    __builtin_amdgcn_global_load_lds((const __attribute__((address_space(1))) unsigned int*)gsrc,
                                     (__attribute__((address_space(3))) unsigned int*)ldst,
                                     16, 0, 0);
}

// ---------------------------------------------------------------- convert x fp32 -> bf16
__global__ __launch_bounds__(256) void convert_x_kernel(const float* __restrict__ x,
                                                        ushort_t* __restrict__ xbf) {
    int i = blockIdx.x * 256 + threadIdx.x;
    const float4 v = reinterpret_cast<const float4*>(x)[i];
    ushort4 o;
    o.x = f2bf(v.x); o.y = f2bf(v.y); o.z = f2bf(v.z); o.w = f2bf(v.w);
    reinterpret_cast<ushort4*>(xbf)[i] = o;
}

// ---------------------------------------------------------------- weight transpose+convert
// in: [K][N] fp32 (expert z at z*K*N), out: [N][K] bf16 (expert z at z*K*N)
__global__ __launch_bounds__(256) void wconv_kernel(const float* __restrict__ in,
                                                    ushort_t* __restrict__ out,
                                                    int K, int N) {
    __shared__ float sT[32][33];
    const int e = blockIdx.z;
    const float* src = in + (size_t)e * K * N;
    ushort_t* dst = out + (size_t)e * K * N;
    const int k0 = blockIdx.y * 32, n0 = blockIdx.x * 32;
    const int r = threadIdx.x >> 3;          // 0..31
    const int c4 = (threadIdx.x & 7) * 4;    // 0..28
    float4 v = *reinterpret_cast<const float4*>(src + (size_t)(k0 + r) * N + n0 + c4);
    sT[r][c4 + 0] = v.x; sT[r][c4 + 1] = v.y; sT[r][c4 + 2] = v.z; sT[r][c4 + 3] = v.w;
    __syncthreads();
    ushort4 o;
    o.x = f2bf(sT[c4 + 0][r]); o.y = f2bf(sT[c4 + 1][r]);
    o.z = f2bf(sT[c4 + 2][r]); o.w = f2bf(sT[c4 + 3][r]);
    *reinterpret_cast<ushort4*>(dst + (size_t)(n0 + r) * K + k0 + c4) = o;
}

// ---------------------------------------------------------------- router (one wave per token)
__global__ __launch_bounds__(256) void router_kernel(const float* __restrict__ x,
                                                     const float* __restrict__ Wg,
                                                     const float* __restrict__ bg,
                                                     float* __restrict__ wts,     // [T][8]
                                                     float* __restrict__ probs,   // [T][8]
                                                     float* __restrict__ ent,     // [T]
                                                     float* __restrict__ act_out) // [T]
{
    int wave = threadIdx.x >> 6;
    int lane = threadIdx.x & 63;
    int t = blockIdx.x * 4 + wave;

    float acc[8];
#pragma unroll
    for (int e = 0; e < 8; ++e) acc[e] = 0.f;

    const float* xrow = x + (size_t)t * D_MODEL;
    for (int d = lane; d < D_MODEL; d += 64) {
        float xv = xrow[d];
        const float4* wg = reinterpret_cast<const float4*>(Wg + (size_t)d * 8);
        float4 a = wg[0], b = wg[1];
        acc[0] += xv * a.x; acc[1] += xv * a.y; acc[2] += xv * a.z; acc[3] += xv * a.w;
        acc[4] += xv * b.x; acc[5] += xv * b.y; acc[6] += xv * b.z; acc[7] += xv * b.w;
    }
#pragma unroll
    for (int e = 0; e < 8; ++e) {
#pragma unroll
        for (int off = 32; off > 0; off >>= 1) acc[e] += __shfl_xor(acc[e], off);
    }

    if (lane == 0) {
        float l[8], p[8];
        float m = -1e30f;
#pragma unroll
        for (int e = 0; e < 8; ++e) { l[e] = acc[e] + bg[e]; m = fmaxf(m, l[e]); }
        float s = 0.f;
#pragma unroll
        for (int e = 0; e < 8; ++e) { p[e] = expf(l[e] - m); s += p[e]; }
        float inv = 1.f / s;
#pragma unroll
        for (int e = 0; e < 8; ++e) p[e] *= inv;

        int idx[8]; float sp[8];
#pragma unroll
        for (int e = 0; e < 8; ++e) { idx[e] = e; sp[e] = p[e]; }
        for (int i = 0; i < 8; ++i) {
            int best = i;
            for (int j = i + 1; j < 8; ++j) if (sp[j] > sp[best]) best = j;
            float tv = sp[i]; sp[i] = sp[best]; sp[best] = tv;
            int ti = idx[i]; idx[i] = idx[best]; idx[best] = ti;
        }
        float cum = 0.f, asum = 0.f, ap[8];
        int cnt = 0;
        for (int i = 0; i < 8; ++i) {
            int active = (i == 0) || (cum < THRESH);
            cum += sp[i];
            ap[i] = active ? sp[i] : 0.f;
            asum += ap[i];
            cnt += active;
        }
        float rinv = 1.f / (asum + EPS_R);
        float w[8];
        for (int i = 0; i < 8; ++i) w[idx[i]] = ap[i] * rinv;

        float* wrow = wts + (size_t)t * 8;
        float* prow = probs + (size_t)t * 8;
        float e_sum = 0.f;
#pragma unroll
        for (int e = 0; e < 8; ++e) {
            wrow[e] = w[e];
            prow[e] = p[e];
            e_sum -= p[e] * logf(p[e] + EPS_R);
        }
        ent[t] = e_sum;
        act_out[t] = (float)cnt;
    }
}

// ---------------------------------------------------------------- per-expert token compaction
// 512 threads = 8 waves; wave e compacts tokens for expert e (ascending t, deterministic)
__global__ __launch_bounds__(512) void build_lists_kernel(const float* __restrict__ wts,
                                                          int* __restrict__ tok,   // [8][T]
                                                          int* __restrict__ pos,   // [T][8]
                                                          int* __restrict__ cnt) { // [8]
    const int e = threadIdx.x >> 6;
    const int lane = threadIdx.x & 63;
    int base = 0;
    for (int t0 = 0; t0 < TOKENS; t0 += 64) {
        int t = t0 + lane;
        float w = wts[(size_t)t * 8 + e];
        unsigned long long mask = __ballot(w > 0.f);
        int rank = __popcll(mask & ((1ull << lane) - 1ull));
        if (w > 0.f) {
            tok[e * TOKENS + base + rank] = t;
            pos[(size_t)t * 8 + e] = base + rank;
        } else {
            pos[(size_t)t * 8 + e] = -1;
        }
        base += __popcll(mask);
    }
    if (lane == 0) cnt[e] = base;
}

// ---------------------------------------------------------------- loss reduce (single block, deterministic)
__global__ __launch_bounds__(256) void loss_kernel(const float* __restrict__ wts,
                                                   const float* __restrict__ probs,
                                                   const float* __restrict__ ent,
                                                   float* __restrict__ out_scalars) // [2]
{
    int tid = threadIdx.x;
    float fsum[8], psum[8], es = 0.f;
#pragma unroll
    for (int e = 0; e < 8; ++e) { fsum[e] = 0.f; psum[e] = 0.f; }
    for (int t = tid; t < TOKENS; t += 256) {
        const float* wrow = wts + (size_t)t * 8;
        const float* prow = probs + (size_t)t * 8;
#pragma unroll
        for (int e = 0; e < 8; ++e) {
            fsum[e] += (wrow[e] > 0.f) ? 1.f : 0.f;
            psum[e] += prow[e];
        }
        es += ent[t];
    }
    __shared__ float red[256];
    __shared__ float tot[17];
    for (int q = 0; q < 17; ++q) {
        float v = (q < 8) ? fsum[q] : ((q < 16) ? psum[q - 8] : es);
        red[tid] = v; __syncthreads();
        for (int s = 128; s > 0; s >>= 1) {
            if (tid < s) red[tid] += red[tid + s];
            __syncthreads();
        }
        if (tid == 0) tot[q] = red[0];
        __syncthreads();
    }
    if (tid == 0) {
        const float invT = 1.f / (float)TOKENS;
        float lb = 0.f;
        for (int e = 0; e < 8; ++e) lb += (tot[e] * invT) * (tot[8 + e] * invT);
        out_scalars[0] = 8.f * lb;
        out_scalars[1] = tot[16] * invT;
    }
}

// ---------------------------------------------------------------- GEMM1 (sparse M): g[e][i] = swiglu(x[tok[e][i]])
// tile 128(M-compacted) x 64(N), BK=64, 4 waves (2x2), dual B (W1,W3)
__global__ __launch_bounds__(256, 2) void gemm1_kernel(const ushort_t* __restrict__ xbf, // [T][1024]
                                                       const ushort_t* __restrict__ w1t, // [GS][4096][1024]
                                                       const ushort_t* __restrict__ w3t,
                                                       const float* __restrict__ b1,     // [E][4096]
                                                       const float* __restrict__ b3,
                                                       const int* __restrict__ tok,      // [8][T]
                                                       const int* __restrict__ cnts,     // [8]
                                                       ushort_t* __restrict__ g,         // [GS][T][4096] compacted
                                                       int gbase) {
    const int z = blockIdx.z;
    const int ge = gbase + z;
    const int cnt = cnts[ge];
    const int m0 = blockIdx.y * 128;
    if (m0 >= cnt) return;

    __shared__ ushort_t sA[128 * 64];
    __shared__ ushort_t sB1[64 * 64];
    __shared__ ushort_t sB3[64 * 64];

    const int tid = threadIdx.x;
    const int lane = tid & 63;
    const int wave = tid >> 6;
    const int wr = wave >> 1, wc = wave & 1;
    const int n0 = blockIdx.x * 64;

    const ushort_t* w1e = w1t + (size_t)z * D_FF * D_MODEL;
    const ushort_t* w3e = w3t + (size_t)z * D_FF * D_MODEL;

    f32x4 acc1[4][2], acc3[4][2];
#pragma unroll
    for (int i = 0; i < 4; ++i)
#pragma unroll
        for (int j = 0; j < 2; ++j) { acc1[i][j] = (f32x4)0.f; acc3[i][j] = (f32x4)0.f; }

    const int srow = tid >> 3;        // 0..31
    const int scol = (tid & 7) * 8;   // bf16 col within 64-wide K slice

    // indirect A row base pointers (token gather), clamped for tail tiles
    const ushort_t* abase[4];
#pragma unroll
    for (int r = 0; r < 4; ++r) {
        int i = m0 + srow + r * 32;
        i = (i < cnt) ? i : (cnt - 1);
        abase[r] = xbf + (size_t)tok[ge * TOKENS + i] * D_MODEL + scol;
    }

    for (int kk = 0; kk < D_MODEL; kk += 64) {
#pragma unroll
        for (int r = 0; r < 4; ++r)
            gload16(abase[r] + kk, sA + r * 2048 + wave * 512);
#pragma unroll
        for (int r = 0; r < 2; ++r) {
            gload16(w1e + (size_t)(n0 + srow + r * 32) * D_MODEL + kk + scol,
                    sB1 + r * 2048 + wave * 512);
            gload16(w3e + (size_t)(n0 + srow + r * 32) * D_MODEL + kk + scol,
                    sB3 + r * 2048 + wave * 512);
        }
        __syncthreads();

#pragma unroll
        for (int ks = 0; ks < 2; ++ks) {
            const int ko = ks * 32 + (lane >> 4) * 8;
            bf16x8 a[4], u1[2], u3[2];
#pragma unroll
            for (int fm = 0; fm < 4; ++fm)
                a[fm] = *reinterpret_cast<const bf16x8*>(&sA[(wr * 64 + fm * 16 + (lane & 15)) * 64 + ko]);
#pragma unroll
            for (int fn = 0; fn < 2; ++fn) {
                u1[fn] = *reinterpret_cast<const bf16x8*>(&sB1[(wc * 32 + fn * 16 + (lane & 15)) * 64 + ko]);
                u3[fn] = *reinterpret_cast<const bf16x8*>(&sB3[(wc * 32 + fn * 16 + (lane & 15)) * 64 + ko]);
            }
#pragma unroll
            for (int fm = 0; fm < 4; ++fm)
#pragma unroll
                for (int fn = 0; fn < 2; ++fn) {
                    acc1[fm][fn] = __builtin_amdgcn_mfma_f32_16x16x32_bf16(a[fm], u1[fn], acc1[fm][fn], 0, 0, 0);
                    acc3[fm][fn] = __builtin_amdgcn_mfma_f32_16x16x32_bf16(a[fm], u3[fn], acc3[fm][fn], 0, 0, 0);
                }
        }
        __syncthreads();
    }

    // epilogue: SwiGLU -> bf16 g (compacted rows, guarded)
    ushort_t* ge_out = g + (size_t)z * TOKENS * D_FF;
#pragma unroll
    for (int fn = 0; fn < 2; ++fn) {
        int col = n0 + wc * 32 + fn * 16 + (lane & 15);
        float bb1 = b1[(size_t)ge * D_FF + col];
        float bb3 = b3[(size_t)ge * D_FF + col];
#pragma unroll
        for (int fm = 0; fm < 4; ++fm) {
#pragma unroll
            for (int r = 0; r < 4; ++r) {
                int row = m0 + wr * 64 + fm * 16 + (lane >> 4) * 4 + r;
                if (row < cnt) {
                    float h1 = acc1[fm][fn][r] + bb1;
                    float h3 = acc3[fm][fn][r] + bb3;
                    float gv = (h1 / (1.f + expf(-h1))) * h3;
                    ge_out[(size_t)row * D_FF + col] = f2bf(gv);
                }
            }
        }
    }
}

// ---------------------------------------------------------------- GEMM2 (sparse M): part[e][i] = w * (g[e][i]@W2 + b2)
__global__ __launch_bounds__(256, 2) void gemm2_kernel(const ushort_t* __restrict__ g,   // [GS][T][4096]
                                                       const ushort_t* __restrict__ w2t, // [GS][1024][4096]
                                                       const float* __restrict__ b2,     // [E][1024]
                                                       const float* __restrict__ wts,    // [T][8]
                                                       const int* __restrict__ tok,      // [8][T]
                                                       const int* __restrict__ cnts,     // [8]
                                                       float* __restrict__ part,         // [E][T][1024] compacted
                                                       int gbase) {
    const int z = blockIdx.z;
    const int ge = gbase + z;
    const int cnt = cnts[ge];
    const int m0 = blockIdx.y * 128;
    if (m0 >= cnt) return;

    __shared__ ushort_t sA[128 * 64];
    __shared__ ushort_t sB[64 * 64];

    const int tid = threadIdx.x;
    const int lane = tid & 63;
    const int wave = tid >> 6;
    const int wr = wave >> 1, wc = wave & 1;
    const int n0 = blockIdx.x * 64;

    const ushort_t* ga = g + (size_t)z * TOKENS * D_FF;
    const ushort_t* w2e = w2t + (size_t)z * D_MODEL * D_FF;

    f32x4 acc[4][2];
#pragma unroll
    for (int i = 0; i < 4; ++i)
#pragma unroll
        for (int j = 0; j < 2; ++j) acc[i][j] = (f32x4)0.f;

    const int srow = tid >> 3;
    const int scol = (tid & 7) * 8;

    for (int kk = 0; kk < D_FF; kk += 64) {
#pragma unroll
        for (int r = 0; r < 4; ++r)
            gload16(ga + (size_t)(m0 + srow + r * 32) * D_FF + kk + scol,
                    sA + r * 2048 + wave * 512);
#pragma unroll
        for (int r = 0; r < 2; ++r)
            gload16(w2e + (size_t)(n0 + srow + r * 32) * D_FF + kk + scol,
                    sB + r * 2048 + wave * 512);
        __syncthreads();

#pragma unroll
        for (int ks = 0; ks < 2; ++ks) {
            const int ko = ks * 32 + (lane >> 4) * 8;
            bf16x8 a[4], b[2];
#pragma unroll
            for (int fm = 0; fm < 4; ++fm)
                a[fm] = *reinterpret_cast<const bf16x8*>(&sA[(wr * 64 + fm * 16 + (lane & 15)) * 64 + ko]);
#pragma unroll
            for (int fn = 0; fn < 2; ++fn)
                b[fn] = *reinterpret_cast<const bf16x8*>(&sB[(wc * 32 + fn * 16 + (lane & 15)) * 64 + ko]);
#pragma unroll
            for (int fm = 0; fm < 4; ++fm)
#pragma unroll
                for (int fn = 0; fn < 2; ++fn)
                    acc[fm][fn] = __builtin_amdgcn_mfma_f32_16x16x32_bf16(a[fm], b[fn], acc[fm][fn], 0, 0, 0);
        }
        __syncthreads();
    }

    float* pe = part + (size_t)ge * TOKENS * D_MODEL;
    float bb2[2];
#pragma unroll
    for (int fn = 0; fn < 2; ++fn)
        bb2[fn] = b2[(size_t)ge * D_MODEL + n0 + wc * 32 + fn * 16 + (lane & 15)];
#pragma unroll
    for (int fm = 0; fm < 4; ++fm) {
#pragma unroll
        for (int r = 0; r < 4; ++r) {
            int row = m0 + wr * 64 + fm * 16 + (lane >> 4) * 4 + r;
            if (row < cnt) {
                float w = wts[(size_t)tok[ge * TOKENS + row] * 8 + ge];
#pragma unroll
                for (int fn = 0; fn < 2; ++fn) {
                    int col = n0 + wc * 32 + fn * 16 + (lane & 15);
                    pe[(size_t)row * D_MODEL + col] = (acc[fm][fn][r] + bb2[fn]) * w;
                }
            }
        }
    }
}

// ---------------------------------------------------------------- final gather-reduce (one block per token)
__global__ __launch_bounds__(256) void reduce_out_kernel(const float* __restrict__ part, // [E][T][1024]
                                                         const int* __restrict__ pos,    // [T][8]
                                                         float* __restrict__ out) {
    const int t = blockIdx.x;
    const int d = threadIdx.x;   // float4 index, 256*4 = 1024
    float4 s = make_float4(0.f, 0.f, 0.f, 0.f);
#pragma unroll
    for (int e = 0; e < 8; ++e) {
        int p = pos[(size_t)t * 8 + e];
        if (p >= 0) {
            float4 v = reinterpret_cast<const float4*>(part + ((size_t)e * TOKENS + p) * D_MODEL)[d];
            s.x += v.x; s.y += v.y; s.z += v.z; s.w += v.w;
        }
    }
    reinterpret_cast<float4*>(out + (size_t)t * D_MODEL)[d] = s;
}

// ---------------------------------------------------------------- launch
extern "C" void kernel_launch(void* const* d_in, const int* in_sizes, int n_in,
                              void* d_out, int out_size, void* d_ws, size_t ws_size,
                              hipStream_t stream) {
    const float* x  = (const float*)d_in[0];
    const float* Wg = (const float*)d_in[1];
    const float* bg = (const float*)d_in[2];
    const float* W1 = (const float*)d_in[3];
    const float* b1 = (const float*)d_in[4];
    const float* W3 = (const float*)d_in[5];
    const float* b3 = (const float*)d_in[6];
    const float* W2 = (const float*)d_in[7];
    const float* b2 = (const float*)d_in[8];
    float* out = (float*)d_out;

    char* wsb = (char*)d_ws;
    ushort_t* xbf  = (ushort_t*)(wsb);                        // 4 MiB
    float*    wts  = (float*)(wsb + (4u << 20));              // 64 KiB
    float*    probs= (float*)(wsb + (4u << 20) + 65536);      // 64 KiB
    float*    ent  = (float*)(wsb + (4u << 20) + 131072);     // 8 KiB
    int*      tok  = (int*)(wsb + (4u << 20) + 139264);       // 64 KiB
    int*      pos  = (int*)(wsb + (4u << 20) + 204800);       // 64 KiB
    int*      cnts = (int*)(wsb + (4u << 20) + 270336);       // 256 B
    float*    part = (float*)(wsb + (8u << 20));              // 64 MiB ([E][T][1024])

    // per-group buffers after part (ends at 72 MiB)
    const size_t BIG0 = (size_t)72 << 20;
    const size_t PER_E = (size_t)40 << 20;   // w1t+w3t+w2t (24 MB) + gbuf (16 MB)
    int GS = 4;
    if (ws_size < BIG0 + 4 * PER_E) GS = 2;
    if (ws_size < BIG0 + 2 * PER_E) GS = 1;

    char* big = wsb + BIG0;
    const size_t W_SZ = (size_t)GS * ((size_t)D_FF * D_MODEL * 2);   // 8 MiB per expert
    ushort_t* w1t  = (ushort_t*)big;
    ushort_t* w3t  = (ushort_t*)(big + W_SZ);
    ushort_t* w2t  = (ushort_t*)(big + 2 * W_SZ);
    ushort_t* gbuf = (ushort_t*)(big + 3 * W_SZ);

    float* out_scalars = out + FINAL_SIZE;        // [2]
    float* out_act     = out + FINAL_SIZE + 2;    // [TOKENS]

    convert_x_kernel<<<TOKENS * D_MODEL / (256 * 4), 256, 0, stream>>>(x, xbf);
    router_kernel<<<TOKENS / 4, 256, 0, stream>>>(x, Wg, bg, wts, probs, ent, out_act);
    build_lists_kernel<<<1, 512, 0, stream>>>(wts, tok, pos, cnts);
    loss_kernel<<<1, 256, 0, stream>>>(wts, probs, ent, out_scalars);

    for (int g0 = 0; g0 < N_EXP; g0 += GS) {
        wconv_kernel<<<dim3(D_FF / 32, D_MODEL / 32, GS), 256, 0, stream>>>(
            W1 + (size_t)g0 * D_MODEL * D_FF, w1t, D_MODEL, D_FF);
        wconv_kernel<<<dim3(D_FF / 32, D_MODEL / 32, GS), 256, 0, stream>>>(
            W3 + (size_t)g0 * D_MODEL * D_FF, w3t, D_MODEL, D_FF);
        wconv_kernel<<<dim3(D_MODEL / 32, D_FF / 32, GS), 256, 0, stream>>>(
            W2 + (size_t)g0 * D_FF * D_MODEL, w2t, D_FF, D_MODEL);

        gemm1_kernel<<<dim3(D_FF / 64, TOKENS / 128, GS), 256, 0, stream>>>(
            xbf, w1t, w3t, b1, b3, tok, cnts, gbuf, g0);
        gemm2_kernel<<<dim3(D_MODEL / 64, TOKENS / 128, GS), 256, 0, stream>>>(
            gbuf, w2t, b2, wts, tok, cnts, part, g0);
    }
    reduce_out_kernel<<<TOKENS, 256, 0, stream>>>(part, pos, out);
}